// Round 12
// baseline (458.631 us; speedup 1.0000x reference)
//
#include <hip/hip_runtime.h>
#include <hip/hip_bf16.h>

#define NAT 4096
#define NXQ 8192
#define DIM 128
#define KNN 16
#define HD  257   // 2*DIM+1
#define NLAYER 3
#define SLOPE 0.2f
#define GN_EPS 1e-5f
#define BIGD 1e30f
#define APB 16    // atoms per block in fused layer

typedef __attribute__((ext_vector_type(4))) float f32x4;

__device__ __forceinline__ float leakyf(float z) { return z >= 0.0f ? z : SLOPE * z; }
__device__ __forceinline__ unsigned long long shfl_xor_u64(unsigned long long v, int m) {
    int lo = __shfl_xor((int)(v & 0xffffffffu), m);
    int hi = __shfl_xor((int)(v >> 32), m);
    return ((unsigned long long)(unsigned)hi << 32) | (unsigned)lo;
}

// ---------------- fill ----------------
__global__ void fill_f32_r12(float* __restrict__ p, int n, float v)
{
    int i = blockIdx.x * 256 + threadIdx.x;
    if (i < n) p[i] = v;
}

// ---------------- initial per-atom feature MLP ----------------
__global__ __launch_bounds__(128) void feat_transform_r12(
    const float* __restrict__ af,
    const float* __restrict__ tw1, const float* __restrict__ tb1,
    const float* __restrict__ tw2, const float* __restrict__ tb2,
    float* __restrict__ out)
{
    const int i = blockIdx.x;
    const int t = threadIdx.x;
    __shared__ __align__(16) float a_s[DIM];
    __shared__ __align__(16) float h_s[DIM];
    a_s[t] = af[i * DIM + t];
    __syncthreads();
    float acc = tb1[t];
    #pragma unroll 2
    for (int k = 0; k < DIM; k += 4) {
        float4 v = *(const float4*)&a_s[k];
        acc = fmaf(v.x, tw1[(k + 0) * DIM + t], acc);
        acc = fmaf(v.y, tw1[(k + 1) * DIM + t], acc);
        acc = fmaf(v.z, tw1[(k + 2) * DIM + t], acc);
        acc = fmaf(v.w, tw1[(k + 3) * DIM + t], acc);
    }
    h_s[t] = leakyf(acc);
    __syncthreads();
    float acc2 = tb2[t];
    #pragma unroll 2
    for (int k = 0; k < DIM; k += 4) {
        float4 v = *(const float4*)&h_s[k];
        acc2 = fmaf(v.x, tw2[(k + 0) * DIM + t], acc2);
        acc2 = fmaf(v.y, tw2[(k + 1) * DIM + t], acc2);
        acc2 = fmaf(v.z, tw2[(k + 2) * DIM + t], acc2);
        acc2 = fmaf(v.w, tw2[(k + 3) * DIM + t], acc2);
    }
    out[i * DIM + t] = acc2;
}

// ---------------- batch segment bounds ----------------
__global__ __launch_bounds__(64) void batch_starts_r12(const int* __restrict__ abatch,
                                                       int* __restrict__ starts)
{
    int t = threadIdx.x;
    if (t <= 8) {
        int lo = 0, hi = NAT;
        while (lo < hi) { int m = (lo + hi) >> 1; if (abatch[m] < t) lo = m + 1; else hi = m; }
        starts[t] = lo;
    }
}

// ---------------- KNN selection body, CAP slots per lane ----------------
template<int CAP>
__device__ __forceinline__ unsigned long long knn_select(
    const float* __restrict__ axyz, int lo, int hi, int l, int self,
    float qx, float qy, float qz)
{
    float d[CAP];
    #pragma unroll
    for (int s = 0; s < CAP; ++s) {
        const int j = lo + s * 64 + l;
        float d2 = BIGD;
        if (j < hi && j != self) {
            float dx = qx - axyz[3 * j];
            float dy = qy - axyz[3 * j + 1];
            float dz = qz - axyz[3 * j + 2];
            d2 = dx * dx + dy * dy + dz * dz;
        }
        d[s] = d2;
    }

    unsigned mask = 0;
    unsigned long long outk = 0;
    #pragma unroll 1
    for (int it = 0; it < KNN; ++it) {
        float bd = BIGD; int bs = 0;
        #pragma unroll
        for (int s = 0; s < CAP; ++s) {
            bool c = !((mask >> s) & 1u) && d[s] < bd;
            bd = c ? d[s] : bd;
            bs = c ? s : bs;
        }
        const int bj = lo + bs * 64 + l;
        unsigned long long mykey = ((unsigned long long)__float_as_uint(bd) << 32) | (unsigned)bj;
        unsigned long long key = mykey;
        #pragma unroll
        for (int m = 32; m >= 1; m >>= 1) {
            unsigned long long o = shfl_xor_u64(key, m);
            key = (o < key) ? o : key;
        }
        if (key == mykey) mask |= 1u << bs;
        if (l == it) outk = key;
    }
    return outk;
}

// ---------------- wave-parallel KNN: one wave per query ----------------
__global__ __launch_bounds__(256) void knn_r12(
    const float* __restrict__ xyz, const int* __restrict__ xbatch,
    const float* __restrict__ axyz, const int* __restrict__ abatch,
    const int* __restrict__ starts,
    int* __restrict__ idx_aa, float* __restrict__ dist_aa,
    int* __restrict__ idx_xa, float* __restrict__ dist_xa)
{
    const int w = blockIdx.x * 4 + (threadIdx.x >> 6);
    if (w >= NAT + NXQ) return;
    const int l = threadIdx.x & 63;
    const bool is_aa = w < NAT;
    const int q = is_aa ? w : w - NAT;
    float qx, qy, qz; int qb;
    if (is_aa) { qx = axyz[3 * q]; qy = axyz[3 * q + 1]; qz = axyz[3 * q + 2]; qb = abatch[q]; }
    else       { qx = xyz[3 * q];  qy = xyz[3 * q + 1];  qz = xyz[3 * q + 2];  qb = xbatch[q]; }
    const int lo = starts[qb];
    const int hi = starts[qb + 1];
    const int self = is_aa ? q : -1;

    const int smax = (hi - lo + 63) >> 6;   // wave-uniform
    unsigned long long outk;
    if (smax <= 10) outk = knn_select<10>(axyz, lo, hi, l, self, qx, qy, qz);
    else            outk = knn_select<16>(axyz, lo, hi, l, self, qx, qy, qz);

    if (l < KNN) {
        unsigned ju = (unsigned)(outk & 0xffffffffu);
        float dw = __uint_as_float((unsigned)(outk >> 32));
        int jc = (ju >= (unsigned)NAT) ? 0 : (int)ju;
        int*   ip = is_aa ? (idx_aa + q * KNN)  : (idx_xa + q * KNN);
        float* dp = is_aa ? (dist_aa + q * KNN) : (dist_xa + q * KNN);
        ip[l] = jc;
        dp[l] = dw;
    }
}

// ---------------- P = src @ w1[128:256, :] (cols 0..256), 16 rows/block, 512 thr ----
__global__ __launch_bounds__(512) void lin128_r12(
    const float* __restrict__ src, const float* __restrict__ w1,
    float* __restrict__ out)
{
    const int t = threadIdx.x;
    const int i0 = blockIdx.x * 16;
    __shared__ __align__(16) float cen_s[16][DIM];
    #pragma unroll
    for (int it = 0; it < 4; ++it) {
        int lin = it * 512 + t;
        int a = lin >> 7, j = lin & 127;
        cen_s[a][j] = src[(size_t)(i0 + a) * DIM + j];
    }
    __syncthreads();

    const float* wbase = w1 + (size_t)128 * HD;
    const int j = t & 255, tg = t >> 8;      // rows 8*tg .. 8*tg+7
    float acc[8];
    #pragma unroll
    for (int r = 0; r < 8; ++r) acc[r] = 0.0f;
    #pragma unroll 4
    for (int k = 0; k < DIM; k += 4) {
        float w0 = wbase[(size_t)(k + 0) * HD + j];
        float wa = wbase[(size_t)(k + 1) * HD + j];
        float wb = wbase[(size_t)(k + 2) * HD + j];
        float wc = wbase[(size_t)(k + 3) * HD + j];
        #pragma unroll
        for (int r = 0; r < 8; ++r) {
            float4 c = *(const float4*)&cen_s[8 * tg + r][k];
            acc[r] = fmaf(c.x, w0, acc[r]);
            acc[r] = fmaf(c.y, wa, acc[r]);
            acc[r] = fmaf(c.z, wb, acc[r]);
            acc[r] = fmaf(c.w, wc, acc[r]);
        }
    }
    #pragma unroll
    for (int r = 0; r < 8; ++r)
        out[(size_t)(i0 + 8 * tg + r) * HD + j] = acc[r];

    // column 256: 32 lanes per row (512 threads cover all 16 rows)
    {
        const int a = t >> 5, l32 = t & 31;
        float p = 0.f;
        #pragma unroll
        for (int m = 0; m < 4; ++m) {
            const int k = l32 + 32 * m;
            p = fmaf(cen_s[a][k], wbase[(size_t)k * HD + 256], p);
        }
        #pragma unroll
        for (int m = 1; m < 32; m <<= 1) p += __shfl_xor(p, m);
        if (l32 == 0) out[(size_t)(i0 + a) * HD + 256] = p;
    }
}

// ---------------- fused layer, 16 atoms/block, 512 threads ----------------
// c1 in regs (8 atoms/thread) -> aggregate (gather P) -> S@w2 -> GN -> residual.
// dst may alias centers (block reads own rows before writing).
__global__ __launch_bounds__(512) void layer_fused_r12(
    const float* __restrict__ centers,
    const float* __restrict__ Pws,
    const int* __restrict__ nidx, const float* __restrict__ ndist,
    const float* __restrict__ w1, const float* __restrict__ b1,
    const float* __restrict__ w2, const float* __restrict__ b2,
    const float* __restrict__ gw, const float* __restrict__ gb,
    float* __restrict__ dst)
{
    const int t = threadIdx.x;
    const int i0 = blockIdx.x * APB;

    __shared__ __align__(16) float cen_s[APB][DIM];
    __shared__ __align__(16) float S_s[APB][260];
    __shared__ int   eidx_s[APB][KNN];
    __shared__ float edist_s[APB][KNN];
    __shared__ float c1_256_s[APB];

    // ---- stage in ----
    #pragma unroll
    for (int it = 0; it < 4; ++it) {
        int lin = it * 512 + t;
        int a = lin >> 7, j = lin & 127;
        cen_s[a][j] = centers[(size_t)(i0 + a) * DIM + j];
    }
    if (t < APB * KNN) {                       // 256 threads
        int a = t >> 4, e = t & 15;
        eidx_s[a][e]  = nidx[(size_t)(i0 + a) * KNN + e];
        edist_s[a][e] = ndist[(size_t)(i0 + a) * KNN + e];
    }
    __syncthreads();

    // ---- c1: col jc for atoms 8*tg .. 8*tg+7, in registers ----
    const int jc = t & 255, tg = t >> 8;
    float c1a[8];
    {
        const float b = b1[jc];
        #pragma unroll
        for (int r = 0; r < 8; ++r) c1a[r] = b;
    }
    #pragma unroll 4
    for (int k = 0; k < DIM; k += 4) {
        float w0 = w1[(size_t)(k + 0) * HD + jc];
        float wa = w1[(size_t)(k + 1) * HD + jc];
        float wb = w1[(size_t)(k + 2) * HD + jc];
        float wc = w1[(size_t)(k + 3) * HD + jc];
        #pragma unroll
        for (int r = 0; r < 8; ++r) {
            float4 c = *(const float4*)&cen_s[8 * tg + r][k];
            c1a[r] = fmaf(c.x, w0, c1a[r]);
            c1a[r] = fmaf(c.y, wa, c1a[r]);
            c1a[r] = fmaf(c.z, wb, c1a[r]);
            c1a[r] = fmaf(c.w, wc, c1a[r]);
        }
    }
    // c1 col 256: 32 lanes per atom (512 threads cover 16 atoms)
    {
        const int a = t >> 5, l32 = t & 31;
        float p = 0.f;
        #pragma unroll
        for (int m = 0; m < 4; ++m) {
            const int k = l32 + 32 * m;
            p = fmaf(cen_s[a][k], w1[(size_t)k * HD + 256], p);
        }
        #pragma unroll
        for (int m = 1; m < 32; m <<= 1) p += __shfl_xor(p, m);
        if (l32 == 0) c1_256_s[a] = p + b1[256];
    }
    __syncthreads();

    // ---- aggregate: S[a][jc] = sum_e leaky(c1 + P[idx][jc] + d*wd) ----
    {
        const float wd = w1[(size_t)256 * HD + jc];
        float sa[8];
        #pragma unroll
        for (int r = 0; r < 8; ++r) sa[r] = 0.f;
        #pragma unroll 4
        for (int e = 0; e < KNN; ++e) {
            float pv[8];
            #pragma unroll
            for (int r = 0; r < 8; ++r)
                pv[r] = Pws[(size_t)eidx_s[8 * tg + r][e] * HD + jc];
            #pragma unroll
            for (int r = 0; r < 8; ++r)
                sa[r] += leakyf(fmaf(edist_s[8 * tg + r][e], wd, c1a[r] + pv[r]));
        }
        #pragma unroll
        for (int r = 0; r < 8; ++r) S_s[8 * tg + r][jc] = sa[r];
    }
    // col 256 (threads 0..255): a = t>>4, e = t&15
    if (t < APB * KNN) {
        const int a = t >> 4, e = t & 15;
        const float wt = w1[(size_t)256 * HD + 256];
        float h = leakyf(fmaf(edist_s[a][e], wt,
                              c1_256_s[a] + Pws[(size_t)eidx_s[a][e] * HD + 256]));
        #pragma unroll
        for (int m = 1; m < 16; m <<= 1) h += __shfl_xor(h, m);
        if (e == 0) S_s[a][256] = h;
    }
    __syncthreads();

    // ---- stage D: 4 atoms (4*tg2 .. 4*tg2+3) x col j ----
    const int j = t & 127, tg2 = t >> 7;            // tg2 in 0..3
    const int ab = 4 * tg2;
    float macc0 = 16.0f * b2[j], macc1 = macc0, macc2 = macc0, macc3 = macc0;
    #pragma unroll 4
    for (int k = 0; k < 256; k += 4) {
        float w0 = w2[(k + 0) * DIM + j];
        float wa = w2[(k + 1) * DIM + j];
        float wb = w2[(k + 2) * DIM + j];
        float wc = w2[(k + 3) * DIM + j];
        f32x4 s0 = *(const f32x4*)&S_s[ab + 0][k];
        f32x4 s1 = *(const f32x4*)&S_s[ab + 1][k];
        f32x4 s2 = *(const f32x4*)&S_s[ab + 2][k];
        f32x4 s3 = *(const f32x4*)&S_s[ab + 3][k];
        macc0 = fmaf(s0[0], w0, macc0); macc0 = fmaf(s0[1], wa, macc0);
        macc0 = fmaf(s0[2], wb, macc0); macc0 = fmaf(s0[3], wc, macc0);
        macc1 = fmaf(s1[0], w0, macc1); macc1 = fmaf(s1[1], wa, macc1);
        macc1 = fmaf(s1[2], wb, macc1); macc1 = fmaf(s1[3], wc, macc1);
        macc2 = fmaf(s2[0], w0, macc2); macc2 = fmaf(s2[1], wa, macc2);
        macc2 = fmaf(s2[2], wb, macc2); macc2 = fmaf(s2[3], wc, macc2);
        macc3 = fmaf(s3[0], w0, macc3); macc3 = fmaf(s3[1], wa, macc3);
        macc3 = fmaf(s3[2], wb, macc3); macc3 = fmaf(s3[3], wc, macc3);
    }
    {
        const float w256 = w2[256 * DIM + j];
        macc0 = fmaf(S_s[ab + 0][256], w256, macc0);
        macc1 = fmaf(S_s[ab + 1][256], w256, macc1);
        macc2 = fmaf(S_s[ab + 2][256], w256, macc2);
        macc3 = fmaf(S_s[ab + 3][256], w256, macc3);
    }

    // GroupNorm: wave covers one 64-col group of atoms ab..ab+3
    const float gwj = gw[j], gbj = gb[j];
    float m0 = macc0, m1 = macc1, m2 = macc2, m3 = macc3;
    #pragma unroll
    for (int m = 1; m < 64; m <<= 1) {
        m0 += __shfl_xor(m0, m); m1 += __shfl_xor(m1, m);
        m2 += __shfl_xor(m2, m); m3 += __shfl_xor(m3, m);
    }
    const float mu0 = m0 * (1.f / 64.f), mu1 = m1 * (1.f / 64.f);
    const float mu2 = m2 * (1.f / 64.f), mu3 = m3 * (1.f / 64.f);
    float d0 = macc0 - mu0, d1 = macc1 - mu1, d2 = macc2 - mu2, d3 = macc3 - mu3;
    float v0 = d0 * d0, v1 = d1 * d1, v2 = d2 * d2, v3 = d3 * d3;
    #pragma unroll
    for (int m = 1; m < 64; m <<= 1) {
        v0 += __shfl_xor(v0, m); v1 += __shfl_xor(v1, m);
        v2 += __shfl_xor(v2, m); v3 += __shfl_xor(v3, m);
    }
    v0 *= (1.f / 64.f); v1 *= (1.f / 64.f); v2 *= (1.f / 64.f); v3 *= (1.f / 64.f);
    const float y0 = fmaf(d0 * rsqrtf(v0 + GN_EPS), gwj, gbj);
    const float y1 = fmaf(d1 * rsqrtf(v1 + GN_EPS), gwj, gbj);
    const float y2 = fmaf(d2 * rsqrtf(v2 + GN_EPS), gwj, gbj);
    const float y3 = fmaf(d3 * rsqrtf(v3 + GN_EPS), gwj, gbj);
    dst[(size_t)(i0 + ab + 0) * DIM + j] = cen_s[ab + 0][j] + leakyf(y0);
    dst[(size_t)(i0 + ab + 1) * DIM + j] = cen_s[ab + 1][j] + leakyf(y1);
    dst[(size_t)(i0 + ab + 2) * DIM + j] = cen_s[ab + 2][j] + leakyf(y2);
    dst[(size_t)(i0 + ab + 3) * DIM + j] = cen_s[ab + 3][j] + leakyf(y3);
}

extern "C" void kernel_launch(void* const* d_in, const int* in_sizes, int n_in,
                              void* d_out, int out_size, void* d_ws, size_t ws_size,
                              hipStream_t stream)
{
    const size_t out_bytes = (size_t)out_size * sizeof(float);
    if (n_in != 21) { (void)hipMemsetAsync(d_out, 0x43, out_bytes, stream); return; }

    const size_t n_atoms_f = (size_t)NAT * DIM;
    const size_t n_emb_f   = (size_t)NXQ * DIM;
    const size_t n_P_f     = (size_t)NAT * HD;
    const size_t floats_needed = n_atoms_f * 2 + n_emb_f
        + (size_t)NAT * KNN * 2 + (size_t)NXQ * KNN * 2 + n_P_f + 16;
    if (ws_size < floats_needed * 4 + 64) {
        (void)hipMemsetAsync(d_out, 0x41, out_bytes, stream);
        return;
    }

    const float* xyz    = (const float*)d_in[0];
    const float* axyz   = (const float*)d_in[1];
    const float* af     = (const float*)d_in[2];
    const int*   xbatch = (const int*)d_in[3];
    const int*   abatch = (const int*)d_in[4];
    const float* tw1    = (const float*)d_in[5];
    const float* tb1    = (const float*)d_in[6];
    const float* tw2    = (const float*)d_in[7];
    const float* tb2    = (const float*)d_in[8];
    const float* aa_w1  = (const float*)d_in[9];
    const float* aa_b1  = (const float*)d_in[10];
    const float* aa_w2  = (const float*)d_in[11];
    const float* aa_b2  = (const float*)d_in[12];
    const float* aa_gw  = (const float*)d_in[13];
    const float* aa_gb  = (const float*)d_in[14];
    const float* ae_w1  = (const float*)d_in[15];
    const float* ae_b1  = (const float*)d_in[16];
    const float* ae_w2  = (const float*)d_in[17];
    const float* ae_b2  = (const float*)d_in[18];
    const float* ae_gw  = (const float*)d_in[19];
    const float* ae_gb  = (const float*)d_in[20];

    float* fp      = (float*)d_ws;
    float* atoms_a = fp;                 fp += n_atoms_f;
    float* atoms_b = fp;                 fp += n_atoms_f;
    float* emb     = fp;                 fp += n_emb_f;
    int*   idx_aa  = (int*)fp;           fp += (size_t)NAT * KNN;
    float* dist_aa = fp;                 fp += (size_t)NAT * KNN;
    int*   idx_xa  = (int*)fp;           fp += (size_t)NXQ * KNN;
    float* dist_xa = fp;                 fp += (size_t)NXQ * KNN;
    float* Pws     = fp;                 fp += n_P_f;
    int*   bstarts = (int*)fp;           fp += 16;

    const int NOUT = NXQ * DIM;

    fill_f32_r12<<<(NOUT + 255) / 256, 256, 0, stream>>>(emb, NOUT, 1.0f);
    feat_transform_r12<<<NAT, 128, 0, stream>>>(af, tw1, tb1, tw2, tb2, atoms_a);
    batch_starts_r12<<<1, 64, 0, stream>>>(abatch, bstarts);
    knn_r12<<<(NAT + NXQ + 3) / 4, 256, 0, stream>>>(
        xyz, xbatch, axyz, abatch, bstarts, idx_aa, dist_aa, idx_xa, dist_xa);

    // ---- atom-atom layers ----
    float* cur = atoms_a;
    float* nxt = atoms_b;
    for (int i = 0; i < NLAYER; ++i) {
        const float* w1p = aa_w1 + (size_t)i * HD * HD;
        lin128_r12<<<NAT / 16, 512, 0, stream>>>(cur, w1p, Pws);
        layer_fused_r12<<<NAT / APB, 512, 0, stream>>>(
            cur, Pws, idx_aa, dist_aa,
            w1p, aa_b1 + (size_t)i * HD,
            aa_w2 + (size_t)i * HD * DIM, aa_b2 + (size_t)i * DIM,
            aa_gw + (size_t)i * DIM, aa_gb + (size_t)i * DIM, nxt);
        float* tmp = cur; cur = nxt; nxt = tmp;
    }
    const float* atoms_final = cur;

    // ---- xyz-atom layers (emb updated in place; last layer writes d_out) ----
    for (int i = 0; i < NLAYER; ++i) {
        const float* w1p = ae_w1 + (size_t)i * HD * HD;
        lin128_r12<<<NAT / 16, 512, 0, stream>>>(atoms_final, w1p, Pws);
        float* dsti = (i == NLAYER - 1) ? (float*)d_out : emb;
        layer_fused_r12<<<NXQ / APB, 512, 0, stream>>>(
            emb, Pws, idx_xa, dist_xa,
            w1p, ae_b1 + (size_t)i * HD,
            ae_w2 + (size_t)i * HD * DIM, ae_b2 + (size_t)i * DIM,
            ae_gw + (size_t)i * DIM, ae_gb + (size_t)i * DIM, dsti);
    }
}